// Round 5
// baseline (1543.288 us; speedup 1.0000x reference)
//
#include <hip/hip_runtime.h>
#include <hip/hip_bf16.h>
#include <math.h>

#define T_STEPS 512
#define BATCH   1024
#define NB      16
#define NTILE   (BATCH / NB)   // 64 blocks per recurrence kernel

typedef __attribute__((ext_vector_type(8))) short short8;
typedef __attribute__((ext_vector_type(4))) float f32x4;

__device__ __forceinline__ float fast_sigm(float z) {
    return __fdividef(1.0f, 1.0f + __expf(-z));
}
__device__ __forceinline__ float fast_tanh(float z) {
    return fmaf(2.0f, __fdividef(1.0f, 1.0f + __expf(-2.0f * z)), -1.0f);
}
__device__ __forceinline__ unsigned short f2bf(float f) {
    unsigned int u = __float_as_uint(f);
    u += 0x7fffu + ((u >> 16) & 1u);
    return (unsigned short)(u >> 16);
}
__device__ __forceinline__ float bf2f(unsigned short s) {
    return __uint_as_float(((unsigned int)s) << 16);
}
__device__ __forceinline__ short8 ldfrag(const float* __restrict__ p) {
    short8 r;
#pragma unroll
    for (int e = 0; e < 8; ++e) r[e] = (short)f2bf(p[e]);
    return r;
}

// L2 c-update: read the 4 gate activations for (batch=lr, units u0..u0+7) from
// acts, advance c2, emit h2 both as floats and as a bf16 A-fragment.
__device__ __forceinline__ void l2_cupdate(const float* __restrict__ ap, int u0,
                                           float* c2, short8& ah2, float* h2v)
{
    float gi[8], gf[8], gg[8], go[8];
    *(float4*)&gi[0] = *(const float4*)(ap + 0 * 32 + u0);
    *(float4*)&gi[4] = *(const float4*)(ap + 0 * 32 + u0 + 4);
    *(float4*)&gf[0] = *(const float4*)(ap + 1 * 32 + u0);
    *(float4*)&gf[4] = *(const float4*)(ap + 1 * 32 + u0 + 4);
    *(float4*)&gg[0] = *(const float4*)(ap + 2 * 32 + u0);
    *(float4*)&gg[4] = *(const float4*)(ap + 2 * 32 + u0 + 4);
    *(float4*)&go[0] = *(const float4*)(ap + 3 * 32 + u0);
    *(float4*)&go[4] = *(const float4*)(ap + 3 * 32 + u0 + 4);
#pragma unroll
    for (int e = 0; e < 8; ++e) {
        c2[e] = fmaf(gf[e], c2[e], gi[e] * gg[e]);
        const float h = go[e] * fast_tanh(c2[e]);
        h2v[e] = h;
        ah2[e] = (short)f2bf(h);
    }
}

// ===========================================================================
// K1: layer-1 REVERSE recurrence. 64 blocks x 256 threads (4 waves, all hot).
// Wave wv owns units [16wv,16wv+16) x 4 gates; MFMA 16x16x32 bf16, in-lane
// gate combination (C layout: col=lane&15 -> unit, row=(lane>>4)*4+j -> batch).
// h_r archived to ws (bf16) for K2.
// ===========================================================================
__global__ __launch_bounds__(256) void l1rev_kernel(
    const float* __restrict__ x,
    const float* __restrict__ whh1r, const float* __restrict__ wih1r,
    const float* __restrict__ b1r,
    unsigned short* __restrict__ arch)     // [NTILE][T][NB][64]
{
    __shared__ __align__(16) float xT[T_STEPS][20];
    __shared__ __align__(16) short hrT[2][16][72];

    const int blk = blockIdx.x;
    const int tid = threadIdx.x;
    const int wv  = tid >> 6;
    const int l   = tid & 63;
    const int lg  = l >> 4;    // k-group / batch-row group
    const int lr  = l & 15;    // A row (batch) on read, unit col on write
    unsigned short* __restrict__ archb = arch + (size_t)blk * T_STEPS * NB * 64;

    for (int i = tid; i < T_STEPS * NB; i += 256) {
        const int b = i >> 9, t = i & 511;
        xT[t][b] = x[((size_t)(blk * NB + b)) * T_STEPS + t];
    }
    for (int i = tid; i < 16 * 72; i += 256) hrT[0][i / 72][i % 72] = 0;

    short8 BW[8]; float wihv[4], bvv[4];
#pragma unroll
    for (int g = 0; g < 4; ++g) {
        const int row = g * 64 + wv * 16 + lr;
        BW[2 * g]     = ldfrag(whh1r + row * 64 + lg * 8);
        BW[2 * g + 1] = ldfrag(whh1r + row * 64 + 32 + lg * 8);
        wihv[g] = wih1r[row]; bvv[g] = b1r[row];
    }
    float c[4] = {0.f, 0.f, 0.f, 0.f};
    __syncthreads();

    for (int t = T_STEPS - 1; t >= 0; --t) {
        const int rp = (t + 1) & 1;
        const short8 a0 = *(const short8*)&hrT[rp][lr][lg * 8];
        const short8 a1 = *(const short8*)&hrT[rp][lr][32 + lg * 8];
        f32x4 z[4];
#pragma unroll
        for (int g = 0; g < 4; ++g) {
            f32x4 za = {0.f, 0.f, 0.f, 0.f}, zb = {0.f, 0.f, 0.f, 0.f};
            za = __builtin_amdgcn_mfma_f32_16x16x32_bf16(a0, BW[2 * g], za, 0, 0, 0);
            zb = __builtin_amdgcn_mfma_f32_16x16x32_bf16(a1, BW[2 * g + 1], zb, 0, 0, 0);
            z[g] = za + zb;
        }
        const float4 x4 = *(const float4*)&xT[t][lg * 4];
        const float xa[4] = {x4.x, x4.y, x4.z, x4.w};
#pragma unroll
        for (int j = 0; j < 4; ++j) {
            const float vi = fast_sigm(z[0][j] + fmaf(xa[j], wihv[0], bvv[0]));
            const float vf = fast_sigm(z[1][j] + fmaf(xa[j], wihv[1], bvv[1]));
            const float vg = fast_tanh(z[2][j] + fmaf(xa[j], wihv[2], bvv[2]));
            const float vo = fast_sigm(z[3][j] + fmaf(xa[j], wihv[3], bvv[3]));
            c[j] = fmaf(vf, c[j], vi * vg);
            const float h = vo * fast_tanh(c[j]);
            const unsigned short hb = f2bf(h);
            hrT[t & 1][lg * 4 + j][wv * 16 + lr] = (short)hb;
            archb[((size_t)t * NB + lg * 4 + j) * 64 + wv * 16 + lr] = hb;
        }
        __syncthreads();
    }
}

// ===========================================================================
// K2: layer-1 FORWARD (waves 0-3) + layer-2 forward skewed 1 step (waves 4-7)
// + layer-2 reverse single step + MLP head. 64 blocks x 512 threads.
// ONE barrier per step. L2 wave p owns gate p entirely (rows p*32..p*32+31,
// 2 N-tiles); gate activations go to LDS batch-major; the c-update runs at
// the start of the next iteration and rebuilds h2 as an in-register A-frag.
// ===========================================================================
__global__ __launch_bounds__(512) void l12fwd_kernel(
    const float* __restrict__ x,
    const float* __restrict__ wih1f, const float* __restrict__ whh1f, const float* __restrict__ b1f,
    const float* __restrict__ wih2f, const float* __restrict__ whh2f, const float* __restrict__ b2f,
    const float* __restrict__ wih2r, const float* __restrict__ b2r,
    const float* __restrict__ w_fc1, const float* __restrict__ b_fc1,
    const float* __restrict__ w_out, const float* __restrict__ b_out,
    const unsigned short* __restrict__ arch,
    float* __restrict__ out)
{
    __shared__ __align__(16) float xT[T_STEPS][20];     // 40 KB
    __shared__ __align__(16) short hfT[2][16][72];      // 4.6 KB
    __shared__ __align__(16) float acts[2][16][132];    // 16.9 KB gate acts, batch-major
    __shared__ __align__(16) float h2last[16][36];
    __shared__ __align__(16) float actsC[4][16][32];
    __shared__ __align__(16) float lastT[16][68];
    __shared__ __align__(16) float zzT[16][68];

    const int blk = blockIdx.x;
    const int tid = threadIdx.x;
    const int wv  = tid >> 6;
    const int l   = tid & 63;
    const int lg  = l >> 4;
    const int lr  = l & 15;
    const unsigned short* __restrict__ archb = arch + (size_t)blk * T_STEPS * NB * 64;

    for (int i = tid; i < T_STEPS * NB; i += 512) {
        const int b = i >> 9, t = i & 511;
        xT[t][b] = x[((size_t)(blk * NB + b)) * T_STEPS + t];
    }
    for (int i = tid; i < 16 * 72; i += 512) hfT[1][i / 72][i % 72] = 0;

    short8 BW[10];                       // w0-3: 8 whh1f frags; w4-7: 10 L2 frags
    float wihv[4], bvv[4];               // waves 0-3
    float b2v[2];                        // waves 4-7
    const int p = wv - 4;                // L2 gate index (waves 4-7)
    if (wv < 4) {
#pragma unroll
        for (int g = 0; g < 4; ++g) {
            const int row = g * 64 + wv * 16 + lr;
            BW[2 * g]     = ldfrag(whh1f + row * 64 + lg * 8);
            BW[2 * g + 1] = ldfrag(whh1f + row * 64 + 32 + lg * 8);
            wihv[g] = wih1f[row]; bvv[g] = b1f[row];
        }
    } else {
#pragma unroll
        for (int q = 0; q < 2; ++q) {
            const int r2 = (p * 2 + q) * 16 + lr;        // gate-row (gate p fixed)
            BW[q * 5 + 0] = ldfrag(wih2f + r2 * 128 + lg * 8);        // hf k 0-31
            BW[q * 5 + 1] = ldfrag(wih2f + r2 * 128 + 32 + lg * 8);   // hf k 32-63
            BW[q * 5 + 2] = ldfrag(wih2f + r2 * 128 + 64 + lg * 8);   // hr k 0-31
            BW[q * 5 + 3] = ldfrag(wih2f + r2 * 128 + 96 + lg * 8);   // hr k 32-63
            BW[q * 5 + 4] = ldfrag(whh2f + r2 * 32 + lg * 8);         // h2 k 0-31
            b2v[q] = b2f[r2];
        }
    }

    float c1[4] = {0.f, 0.f, 0.f, 0.f};
    float c2[8] = {0.f, 0.f, 0.f, 0.f, 0.f, 0.f, 0.f, 0.f};
    float h2v[8];
    short8 ah2 = {0, 0, 0, 0, 0, 0, 0, 0};
    short8 nxt0 = {}, nxt1 = {};
    if (wv >= 4) {   // prefetch hr(0)
        const unsigned short* pp = archb + (size_t)lr * 64 + lg * 8;
        nxt0 = *(const short8*)pp;
        nxt1 = *(const short8*)(pp + 32);
    }
    __syncthreads();

    for (int t = 0; t <= T_STEPS; ++t) {
        if (wv < 4) {
            if (t < T_STEPS) {
                const int rp = (t + 1) & 1;
                const short8 a0 = *(const short8*)&hfT[rp][lr][lg * 8];
                const short8 a1 = *(const short8*)&hfT[rp][lr][32 + lg * 8];
                f32x4 z[4];
#pragma unroll
                for (int g = 0; g < 4; ++g) {
                    f32x4 za = {0.f, 0.f, 0.f, 0.f}, zb = {0.f, 0.f, 0.f, 0.f};
                    za = __builtin_amdgcn_mfma_f32_16x16x32_bf16(a0, BW[2 * g], za, 0, 0, 0);
                    zb = __builtin_amdgcn_mfma_f32_16x16x32_bf16(a1, BW[2 * g + 1], zb, 0, 0, 0);
                    z[g] = za + zb;
                }
                const float4 x4 = *(const float4*)&xT[t][lg * 4];
                const float xa[4] = {x4.x, x4.y, x4.z, x4.w};
#pragma unroll
                for (int j = 0; j < 4; ++j) {
                    const float vi = fast_sigm(z[0][j] + fmaf(xa[j], wihv[0], bvv[0]));
                    const float vf = fast_sigm(z[1][j] + fmaf(xa[j], wihv[1], bvv[1]));
                    const float vg = fast_tanh(z[2][j] + fmaf(xa[j], wihv[2], bvv[2]));
                    const float vo = fast_sigm(z[3][j] + fmaf(xa[j], wihv[3], bvv[3]));
                    c1[j] = fmaf(vf, c1[j], vi * vg);
                    const float h = vo * fast_tanh(c1[j]);
                    hfT[t & 1][lg * 4 + j][wv * 16 + lr] = (short)f2bf(h);
                }
            }
        } else if (t >= 1) {
            // (a) advance c2 to step s-1 = t-2, rebuild h2 A-frag in registers
            if (t >= 2) l2_cupdate(&acts[(t - 1) & 1][lr][0], lg * 8, c2, ah2, h2v);
            // (b) z(s) = Wih2f.[hf(s); hr(s)] + Whh2f.h2(s-1) + b
            const int rp = (t + 1) & 1;
            const short8 af0 = *(const short8*)&hfT[rp][lr][lg * 8];
            const short8 af1 = *(const short8*)&hfT[rp][lr][32 + lg * 8];
            const short8 hr0 = nxt0, hr1 = nxt1;
            if (t < T_STEPS) {   // prefetch hr(t) for next iteration
                const unsigned short* pp = archb + ((size_t)t * NB + lr) * 64 + lg * 8;
                nxt0 = *(const short8*)pp;
                nxt1 = *(const short8*)(pp + 32);
            }
#pragma unroll
            for (int q = 0; q < 2; ++q) {
                f32x4 za = {0.f, 0.f, 0.f, 0.f}, zb = {0.f, 0.f, 0.f, 0.f};
                za = __builtin_amdgcn_mfma_f32_16x16x32_bf16(af0, BW[q * 5 + 0], za, 0, 0, 0);
                za = __builtin_amdgcn_mfma_f32_16x16x32_bf16(hr0, BW[q * 5 + 2], za, 0, 0, 0);
                zb = __builtin_amdgcn_mfma_f32_16x16x32_bf16(af1, BW[q * 5 + 1], zb, 0, 0, 0);
                zb = __builtin_amdgcn_mfma_f32_16x16x32_bf16(hr1, BW[q * 5 + 3], zb, 0, 0, 0);
                zb = __builtin_amdgcn_mfma_f32_16x16x32_bf16(ah2, BW[q * 5 + 4], zb, 0, 0, 0);
                const int rowb = (p * 2 + q) * 16 + lr;
#pragma unroll
                for (int j = 0; j < 4; ++j) {
                    const float zz = za[j] + zb[j] + b2v[q];
                    acts[t & 1][lg * 4 + j][rowb] = (p == 2) ? fast_tanh(zz) : fast_sigm(zz);
                }
            }
        }
        __syncthreads();
    }

    // final L2 c-update (s=511; acts(511) is in buffer 0); wave 4 publishes h2f(511)
    if (wv >= 4) {
        l2_cupdate(&acts[0][lr][0], lg * 8, c2, ah2, h2v);
        if (wv == 4) {
#pragma unroll
            for (int e = 0; e < 8; ++e) h2last[lr][lg * 8 + e] = h2v[e];
        }
    }
    __syncthreads();

    // ===== Phase C: layer-2 reverse single step @ t=T-1 + MLP head =========
    {
        const int rr = tid & 127;
        const int bq = tid >> 7;   // 0..3
        const float* __restrict__ wr = wih2r + rr * 128;
        const int gate = rr >> 5, un = rr & 31;
#pragma unroll
        for (int jb = 0; jb < 4; ++jb) {
            const int b = bq * 4 + jb;
            float a0 = b2r[rr], a1 = 0.f;
            const unsigned short* hrp = archb + ((size_t)(T_STEPS - 1) * NB + b) * 64;
#pragma unroll
            for (int ub = 0; ub < 8; ++ub) {
                const short8 hv = *(const short8*)&hfT[1][b][ub * 8];
                const short8 rv = *(const short8*)(hrp + ub * 8);
#pragma unroll
                for (int e = 0; e < 8; ++e) {
                    a0 = fmaf(wr[ub * 8 + e],      bf2f((unsigned short)hv[e]), a0);
                    a1 = fmaf(wr[64 + ub * 8 + e], bf2f((unsigned short)rv[e]), a1);
                }
            }
            const float zv = a0 + a1;
            actsC[gate][b][un] = (gate == 2) ? fast_tanh(zv) : fast_sigm(zv);
        }
        __syncthreads();
        {
            const int b = tid >> 5, u = tid & 31;
            const float cr = actsC[0][b][u] * actsC[2][b][u];   // c0 = 0
            lastT[b][32 + u] = actsC[3][b][u] * fast_tanh(cr);
            lastT[b][u]      = h2last[b][u];
        }
        __syncthreads();
        {
            const int row = tid & 63, bg = tid >> 6;
            const float* __restrict__ wf = w_fc1 + row * 64;
#pragma unroll
            for (int jb = 0; jb < 2; ++jb) {
                const int b = bg * 2 + jb;
                float acc = b_fc1[row];
#pragma unroll
                for (int u4 = 0; u4 < 16; ++u4) {
                    const float4 lv = *(const float4*)&lastT[b][u4 * 4];
                    const float4 w4 = *(const float4*)&wf[u4 * 4];
                    acc = fmaf(w4.x, lv.x, acc);
                    acc = fmaf(w4.y, lv.y, acc);
                    acc = fmaf(w4.z, lv.z, acc);
                    acc = fmaf(w4.w, lv.w, acc);
                }
                zzT[b][row] = fmaxf(acc, 0.f) * w_out[row];
            }
        }
        __syncthreads();
        if (tid < NB) {
            float s = 0.f;
#pragma unroll 8
            for (int r = 0; r < 64; ++r) s += zzT[tid][r];
            out[blk * NB + tid] = fast_sigm(s + b_out[0]);
        }
    }
}

// ===========================================================================
// Fallback (ws too small): round-3 kernel, LDS archive, 1024 x 256.
// ===========================================================================
__device__ __forceinline__ float gate_fn(int g, float z) {
    const bool tg = (g == 2);
    const float s = fast_sigm(tg ? 2.0f * z : z);
    return tg ? fmaf(2.0f, s, -1.0f) : s;
}
__device__ __forceinline__ float bflo(unsigned int d) { return __uint_as_float(d << 16); }
__device__ __forceinline__ float bfhi(unsigned int d) { return __uint_as_float(d & 0xffff0000u); }

#define FMA4(acc, wv, hv)                      \
    acc = fmaf((wv).x, (hv).x, acc);           \
    acc = fmaf((wv).y, (hv).y, acc);           \
    acc = fmaf((wv).z, (hv).z, acc);           \
    acc = fmaf((wv).w, (hv).w, acc)

#define BF8(acc0, acc1, dv, wq0, wq1)                          \
    acc0 = fmaf(bflo((dv).x), (wq0).x, acc0);                  \
    acc0 = fmaf(bfhi((dv).x), (wq0).y, acc0);                  \
    acc0 = fmaf(bflo((dv).y), (wq0).z, acc0);                  \
    acc0 = fmaf(bfhi((dv).y), (wq0).w, acc0);                  \
    acc1 = fmaf(bflo((dv).z), (wq1).x, acc1);                  \
    acc1 = fmaf(bfhi((dv).z), (wq1).y, acc1);                  \
    acc1 = fmaf(bflo((dv).w), (wq1).z, acc1);                  \
    acc1 = fmaf(bfhi((dv).w), (wq1).w, acc1)

__global__ __launch_bounds__(256, 2) void bilstm_fused_kernel(
    const float* __restrict__ x,
    const float* __restrict__ wih1f, const float* __restrict__ whh1f, const float* __restrict__ b1f,
    const float* __restrict__ wih1r, const float* __restrict__ whh1r, const float* __restrict__ b1r,
    const float* __restrict__ wih2f, const float* __restrict__ whh2f, const float* __restrict__ b2f,
    const float* __restrict__ wih2r, const float* __restrict__ b2r,
    const float* __restrict__ w_fc1, const float* __restrict__ b_fc1,
    const float* __restrict__ w_out, const float* __restrict__ b_out,
    float* __restrict__ out)
{
    __shared__ __align__(16) unsigned short hr16[T_STEPS * 64];
    __shared__ __align__(16) float xbuf[T_STEPS];
    __shared__ __align__(16) float hrfb[2][64];
    __shared__ __align__(16) float hfbuf[2][64];
    __shared__ __align__(16) float h2buf[2][32];
    __shared__ __align__(16) float g2c[4][32];
    __shared__ __align__(16) float lastbuf[64];

    const int b   = blockIdx.x;
    const int tid = threadIdx.x;

    for (int i = tid; i < T_STEPS; i += 256) xbuf[i] = x[(size_t)b * T_STEPS + i];
    if (tid < 64) { hrfb[0][tid] = 0.0f; hfbuf[1][tid] = 0.0f; }
    if (tid < 32) h2buf[1][tid] = 0.0f;

    float4 W[40];

    {
        const int w   = tid >> 6;
        const int l   = tid & 63;
        const int ul  = l & 15;
        const int g   = l >> 4;
        const int row = g * 64 + w * 16 + ul;
#pragma unroll
        for (int q = 0; q < 16; ++q) W[q] = *(const float4*)(whh1r + row * 64 + q * 4);
        const float wi = wih1r[row];
        const float bb = b1r[row];
        float c = 0.0f;
        __syncthreads();

        for (int t = T_STEPS - 1; t >= 0; --t) {
            const float4* hp = (const float4*)hrfb[(t + 1) & 1];
            float a0 = fmaf(xbuf[t], wi, bb), a1 = 0.0f, a2 = 0.0f, a3 = 0.0f;
#pragma unroll
            for (int q = 0; q < 16; q += 4) {
                FMA4(a0, W[q],     hp[q]);
                FMA4(a1, W[q + 1], hp[q + 1]);
                FMA4(a2, W[q + 2], hp[q + 2]);
                FMA4(a3, W[q + 3], hp[q + 3]);
            }
            const float z = (a0 + a1) + (a2 + a3);
            const float v = gate_fn(g, z);
            const float sf = __shfl_xor(v, 16, 64);
            const float tg = __shfl_xor(v, 32, 64);
            const float so = __shfl_xor(v, 48, 64);
            if (g == 0) {
                c = fmaf(sf, c, v * tg);
                const float h = so * fast_tanh(c);
                hrfb[t & 1][w * 16 + ul] = h;
                hr16[t * 64 + w * 16 + ul] = f2bf(h);
            }
            __syncthreads();
        }
    }

    {
        const int wv = tid >> 6;
        const int l  = tid & 63;
        float wiA = 0.f, wiB = 0.f, bA = 0.f, bB = 0.f, b2v = 0.f;
        int u1 = 0, p1 = 0, u2 = 0, g2 = 0;
        if (wv < 2) {
            u1 = wv * 32 + (l & 31);
            p1 = l >> 5;
            const int rA = p1 * 64 + u1;
            const int rB = 128 + p1 * 64 + u1;
#pragma unroll
            for (int q = 0; q < 16; ++q) {
                W[q]      = *(const float4*)(whh1f + rA * 64 + q * 4);
                W[16 + q] = *(const float4*)(whh1f + rB * 64 + q * 4);
            }
            wiA = wih1f[rA]; wiB = wih1f[rB]; bA = b1f[rA]; bB = b1f[rB];
        } else {
            u2 = (wv - 2) * 16 + (l & 15);
            g2 = l >> 4;
            const int row = g2 * 32 + u2;
#pragma unroll
            for (int q = 0; q < 32; ++q) W[q] = *(const float4*)(wih2f + row * 128 + q * 4);
#pragma unroll
            for (int q = 0; q < 8; ++q) W[32 + q] = *(const float4*)(whh2f + row * 32 + q * 4);
            b2v = b2f[row];
        }

        float c1 = 0.0f, c2 = 0.0f;

        for (int t = 0; t <= T_STEPS; ++t) {
            if (wv < 2) {
                if (t < T_STEPS) {
                    const float4* hp = (const float4*)hfbuf[(t + 1) & 1];
                    const float xt = xbuf[t];
                    float p0 = fmaf(xt, wiA, bA), pp1 = 0.0f;
                    float q0 = fmaf(xt, wiB, bB), qq1 = 0.0f;
#pragma unroll
                    for (int q = 0; q < 16; q += 2) {
                        const float4 h0 = hp[q], h1 = hp[q + 1];
                        FMA4(p0,  W[q],          h0);
                        FMA4(pp1, W[q + 1],      h1);
                        FMA4(q0,  W[16 + q],     h0);
                        FMA4(qq1, W[16 + q + 1], h1);
                    }
                    const float z0 = p0 + pp1, z1 = q0 + qq1;
                    const float v0 = fast_sigm(z0);
                    const float v1 = (p1 == 0) ? fast_tanh(z1) : fast_sigm(z1);
                    const float o0 = __shfl_xor(v0, 32, 64);
                    const float o1 = __shfl_xor(v1, 32, 64);
                    if (p1 == 0) {
                        c1 = fmaf(o0, c1, v0 * v1);
                        hfbuf[t & 1][u1] = o1 * fast_tanh(c1);
                    }
                }
            } else {
                if (t >= 1) {
                    const int s = t - 1;
                    const float4* hf  = (const float4*)hfbuf[(t + 1) & 1];
                    const float4* h2p = (const float4*)h2buf[t & 1];
                    const uint4*  hrp = (const uint4*)(hr16 + s * 64);
                    float a0 = b2v, a1 = 0.0f, a2 = 0.0f, a3 = 0.0f;
#pragma unroll
                    for (int q = 0; q < 16; q += 2) {
                        FMA4(a0, W[q],     hf[q]);
                        FMA4(a1, W[q + 1], hf[q + 1]);
                    }
#pragma unroll
                    for (int q = 0; q < 8; ++q) {
                        const uint4 dv = hrp[q];
                        BF8(a2, a3, dv, W[16 + 2 * q], W[17 + 2 * q]);
                    }
#pragma unroll
                    for (int q = 0; q < 8; q += 2) {
                        FMA4(a0, W[32 + q],     h2p[q]);
                        FMA4(a1, W[32 + q + 1], h2p[q + 1]);
                    }
                    const float z = (a0 + a1) + (a2 + a3);
                    const float v = gate_fn(g2, z);
                    const float sf = __shfl_xor(v, 16, 64);
                    const float tg = __shfl_xor(v, 32, 64);
                    const float so = __shfl_xor(v, 48, 64);
                    if (g2 == 0) {
                        c2 = fmaf(sf, c2, v * tg);
                        h2buf[(t + 1) & 1][u2] = so * fast_tanh(c2);
                    }
                }
            }
            __syncthreads();
        }
    }

    {
        if (tid < 128) {
            const float4* hfl = (const float4*)hfbuf[1];
            const uint4*  hrl = (const uint4*)(hr16 + 511 * 64);
            const float4* wr  = (const float4*)(wih2r + tid * 128);
            float a0 = b2r[tid], a1 = 0.0f, a2 = 0.0f, a3 = 0.0f;
#pragma unroll
            for (int q = 0; q < 16; q += 2) {
                FMA4(a0, wr[q],     hfl[q]);
                FMA4(a1, wr[q + 1], hfl[q + 1]);
            }
#pragma unroll
            for (int q = 0; q < 8; ++q) {
                const uint4 dv = hrl[q];
                BF8(a2, a3, dv, wr[16 + 2 * q], wr[17 + 2 * q]);
            }
            const float z = (a0 + a1) + (a2 + a3);
            g2c[tid >> 5][tid & 31] = gate_fn(tid >> 5, z);
        }
        __syncthreads();
        if (tid < 32) {
            const float cr = g2c[0][tid] * g2c[2][tid];
            lastbuf[32 + tid] = g2c[3][tid] * fast_tanh(cr);
            lastbuf[tid]      = h2buf[1][tid];
        }
        __syncthreads();
        if (tid < 64) {
            const float4* lv = (const float4*)lastbuf;
            float acc = b_fc1[tid];
#pragma unroll
            for (int q = 0; q < 16; ++q) {
                const float4 wvv = *(const float4*)(w_fc1 + tid * 64 + q * 4);
                FMA4(acc, wvv, lv[q]);
            }
            float prod = fmaxf(acc, 0.0f) * w_out[tid];
#pragma unroll
            for (int s2 = 1; s2 < 64; s2 <<= 1) prod += __shfl_xor(prod, s2, 64);
            if (tid == 0) out[b] = fast_sigm(prod + b_out[0]);
        }
    }
}

// ---------------------------------------------------------------------------
extern "C" void kernel_launch(void* const* d_in, const int* in_sizes, int n_in,
                              void* d_out, int out_size, void* d_ws, size_t ws_size,
                              hipStream_t stream) {
    const float* x     = (const float*)d_in[0];
    const float* wih1f = (const float*)d_in[1];
    const float* whh1f = (const float*)d_in[2];
    const float* b1f   = (const float*)d_in[3];
    const float* wih1r = (const float*)d_in[4];
    const float* whh1r = (const float*)d_in[5];
    const float* b1r   = (const float*)d_in[6];
    const float* wih2f = (const float*)d_in[7];
    const float* whh2f = (const float*)d_in[8];
    const float* b2f   = (const float*)d_in[9];
    const float* wih2r = (const float*)d_in[10];
    // d_in[11] = whh2r unused: layer-2 reverse runs exactly one step from zero state
    const float* b2r   = (const float*)d_in[12];
    const float* w_fc1 = (const float*)d_in[13];
    const float* b_fc1 = (const float*)d_in[14];
    const float* w_out = (const float*)d_in[15];
    const float* b_out = (const float*)d_in[16];
    float* out = (float*)d_out;

    const size_t need = (size_t)NTILE * T_STEPS * NB * 64 * sizeof(unsigned short); // 64 MB
    if (ws_size >= need) {
        unsigned short* arch = (unsigned short*)d_ws;
        l1rev_kernel<<<dim3(NTILE), dim3(256), 0, stream>>>(x, whh1r, wih1r, b1r, arch);
        l12fwd_kernel<<<dim3(NTILE), dim3(512), 0, stream>>>(
            x, wih1f, whh1f, b1f, wih2f, whh2f, b2f, wih2r, b2r,
            w_fc1, b_fc1, w_out, b_out, arch, out);
    } else {
        bilstm_fused_kernel<<<dim3(BATCH), dim3(256), 0, stream>>>(
            x, wih1f, whh1f, b1f, wih1r, whh1r, b1r,
            wih2f, whh2f, b2f, wih2r, b2r,
            w_fc1, b_fc1, w_out, b_out, out);
    }
}